// Round 1
// baseline (489.499 us; speedup 1.0000x reference)
//
#include <hip/hip_runtime.h>

// TorchSAT: summed-area-table rectangle sampling.
// sat: (512,512,288) fp32, x: (N,4) fp32 -> out: (N,288) fp32.
// One wave (64 lanes) per output row; per-row case logic is wave-uniform.
// 288 floats = 72 float4 chunks: lane l -> chunk l, lanes 0..7 -> chunk l+64.

constexpr int Hdim = 512;
constexpr int Wdim = 512;
constexpr int Cdim = 288;

__device__ __forceinline__ void sample_acc(const float* __restrict__ sat,
                                           float u0, float u1, float sign,
                                           int lane, float4& a, float4& b) {
    // idx = floor(u*res - 0.5); u*512 is exact in fp32, so this matches numpy.
    int i0 = (int)floorf(u0 * 512.0f - 0.5f);
    int i1 = (int)floorf(u1 * 512.0f - 0.5f);
    // bad if any idx out of [0,512): unsigned trick covers negatives.
    if ((unsigned)i0 >= (unsigned)Hdim || (unsigned)i1 >= (unsigned)Wdim) return;
    const float4* __restrict__ row =
        (const float4*)(sat + (size_t)(i0 * Wdim + i1) * Cdim);
    float4 v = row[lane];
    a.x += sign * v.x; a.y += sign * v.y; a.z += sign * v.z; a.w += sign * v.w;
    if (lane < 8) {
        float4 w = row[lane + 64];
        b.x += sign * w.x; b.y += sign * w.y; b.z += sign * w.z; b.w += sign * w.w;
    }
}

__device__ __forceinline__ void query_acc(const float* __restrict__ sat,
                                          float su, float sv, float eu, float ev,
                                          int lane, float4& a, float4& b) {
    const float du = 1.0f / (float)Hdim;
    const float dv = 1.0f / (float)Wdim;
    // r = sample(euv) + sample(suv - duv) - sample([su-du, ev]) - sample([eu, sv-dv])
    sample_acc(sat, eu, ev, 1.0f, lane, a, b);
    sample_acc(sat, su - du, sv - dv, 1.0f, lane, a, b);
    sample_acc(sat, su - du, ev, -1.0f, lane, a, b);
    sample_acc(sat, eu, sv - dv, -1.0f, lane, a, b);
}

__global__ __launch_bounds__(256) void sat_query_kernel(
    const float* __restrict__ sat, const float* __restrict__ x,
    float* __restrict__ out, int n) {
    int wave = (int)((blockIdx.x * blockDim.x + threadIdx.x) >> 6);
    int lane = (int)(threadIdx.x & 63);
    if (wave >= n) return;

    float4 xr = ((const float4*)x)[wave];
    float cu = xr.x, cv = xr.y, d0 = xr.z, d1 = xr.w;

    const float du = 1.0f / (float)Hdim;
    const float dv = 1.0f / (float)Wdim;

    float su = cu - d0 * 0.5f, eu = cu + d0 * 0.5f;
    float sv = cv - d1 * 0.5f, ev = cv + d1 * 0.5f;
    // where(d<0, swap endpoints)
    float nsu = (d0 < 0.0f) ? eu : su, neu = (d0 < 0.0f) ? su : eu;
    float nsv = (d1 < 0.0f) ? ev : sv, nev = (d1 < 0.0f) ? sv : ev;
    // wrap to [0,1)
    nsu -= floorf(nsu); neu -= floorf(neu);
    nsv -= floorf(nsv); nev -= floorf(nev);

    float sx = nsu, sy = nsv, ex = neu, ey = nev;
    float bru = 1.0f - du * 0.5f, brv = 1.0f - dv * 0.5f;
    float tlu = du * 0.5f, tlv = dv * 0.5f;  // = 1 - bru, 1 - brv

    float4 acc_a = make_float4(0.f, 0.f, 0.f, 0.f);
    float4 acc_b = make_float4(0.f, 0.f, 0.f, 0.f);

    bool wx = (sx > ex), wy = (sy > ey);
    if (!wx && !wy) {
        query_acc(sat, sx, sy, ex, ey, lane, acc_a, acc_b);
    } else if (wx && !wy) {
        query_acc(sat, sx, sy, bru, ey, lane, acc_a, acc_b);
        query_acc(sat, tlu, sy, ex, ey, lane, acc_a, acc_b);
    } else if (!wx && wy) {
        query_acc(sat, sx, sy, ex, brv, lane, acc_a, acc_b);
        query_acc(sat, sx, tlv, ex, ey, lane, acc_a, acc_b);
    } else {
        query_acc(sat, tlu, tlv, ex, ey, lane, acc_a, acc_b);
        query_acc(sat, sx, sy, bru, brv, lane, acc_a, acc_b);
        query_acc(sat, sx, tlv, bru, ey, lane, acc_a, acc_b);
        query_acc(sat, tlu, sy, ex, brv, lane, acc_a, acc_b);
    }

    float4* __restrict__ orow = (float4*)(out + (size_t)wave * Cdim);
    orow[lane] = acc_a;
    if (lane < 8) orow[lane + 64] = acc_b;
}

extern "C" void kernel_launch(void* const* d_in, const int* in_sizes, int n_in,
                              void* d_out, int out_size, void* d_ws, size_t ws_size,
                              hipStream_t stream) {
    const float* sat = (const float*)d_in[0];
    const float* x   = (const float*)d_in[1];
    // d_in[2]=start_idx (-1), d_in[3]=len_idx: out_size == N*288 pins the
    // no-slice path, so they are ignored.
    float* out = (float*)d_out;
    int n = in_sizes[1] / 4;  // x is (N,4)

    int rows_per_block = 4;   // 256 threads = 4 waves
    int blocks = (n + rows_per_block - 1) / rows_per_block;
    sat_query_kernel<<<dim3(blocks), dim3(256), 0, stream>>>(sat, x, out, n);
}

// Round 3
// 476.630 us; speedup vs baseline: 1.0270x; 1.0270x over previous
//
#include <hip/hip_runtime.h>

// TorchSAT: summed-area-table rectangle sampling.
// sat: (512,512,288) fp32, x: (N,4) fp32 -> out: (N,288) fp32.
// One wave per output row; all per-row case logic is wave-uniform.
// R1 -> R2 change: if-converted sample validity (offset,sign) + batched
// unconditional loads (8-deep MLP) + non-divergent tail + NT stores for out.
// R2 -> R3: NT store via native ext_vector_type (HIP float4 class rejected).

constexpr int Hdim = 512;
constexpr int Wdim = 512;
constexpr int Cdim = 288;

typedef float f32x4 __attribute__((ext_vector_type(4)));

// Compute one corner sample's row offset and effective sign (0 if OOB).
__device__ __forceinline__ void prep(float u0, float u1, float s,
                                     int& off, float& sgn) {
    int i0 = (int)floorf(u0 * 512.0f - 0.5f);
    int i1 = (int)floorf(u1 * 512.0f - 0.5f);
    bool ok = ((unsigned)i0 < (unsigned)Hdim) && ((unsigned)i1 < (unsigned)Wdim);
    off = ok ? (i0 * Wdim + i1) * Cdim : 0;
    sgn = ok ? s : 0.0f;
}

// One SAT rectangle query = 4 corner samples with signs (+,+,-,-).
__device__ __forceinline__ void prep_query(float su, float sv, float eu, float ev,
                                           int* off, float* sgn) {
    const float du = 1.0f / (float)Hdim;
    const float dv = 1.0f / (float)Wdim;
    prep(eu, ev, 1.0f, off[0], sgn[0]);
    prep(su - du, sv - dv, 1.0f, off[1], sgn[1]);
    prep(su - du, ev, -1.0f, off[2], sgn[2]);
    prep(eu, sv - dv, -1.0f, off[3], sgn[3]);
}

// Issue K samples' loads back-to-back (deep MLP), then accumulate.
// widx = (lane&7)+64 keeps the tail load in-row and non-divergent;
// tmask zeroes the tail contribution for lanes >= 8.
template <int K>
__device__ __forceinline__ void gather(const float* __restrict__ sat,
                                       const int* off, const float* sgn,
                                       int lane, int widx, float tmask,
                                       f32x4& a, f32x4& b) {
    f32x4 v[K], w[K];
#pragma unroll
    for (int k = 0; k < K; ++k) {
        const f32x4* __restrict__ row = (const f32x4*)(sat + off[k]);
        v[k] = row[lane];
        w[k] = row[widx];
    }
#pragma unroll
    for (int k = 0; k < K; ++k) {
        float s = sgn[k];
        float t = s * tmask;
        a += s * v[k];
        b += t * w[k];
    }
}

__global__ __launch_bounds__(256) void sat_query_kernel(
    const float* __restrict__ sat, const float* __restrict__ x,
    float* __restrict__ out, int n) {
    int wave = (int)((blockIdx.x * blockDim.x + threadIdx.x) >> 6);
    int lane = (int)(threadIdx.x & 63);
    if (wave >= n) return;

    float4 xr = ((const float4*)x)[wave];
    float cu = xr.x, cv = xr.y, d0 = xr.z, d1 = xr.w;

    const float du = 1.0f / (float)Hdim;
    const float dv = 1.0f / (float)Wdim;

    float su = cu - d0 * 0.5f, eu = cu + d0 * 0.5f;
    float sv = cv - d1 * 0.5f, ev = cv + d1 * 0.5f;
    float nsu = (d0 < 0.0f) ? eu : su, neu = (d0 < 0.0f) ? su : eu;
    float nsv = (d1 < 0.0f) ? ev : sv, nev = (d1 < 0.0f) ? sv : ev;
    nsu -= floorf(nsu); neu -= floorf(neu);
    nsv -= floorf(nsv); nev -= floorf(nev);

    float sx = nsu, sy = nsv, ex = neu, ey = nev;
    float bru = 1.0f - du * 0.5f, brv = 1.0f - dv * 0.5f;
    float tlu = du * 0.5f, tlv = dv * 0.5f;

    f32x4 acc_a = {0.f, 0.f, 0.f, 0.f};
    f32x4 acc_b = {0.f, 0.f, 0.f, 0.f};

    int widx = (lane & 7) + 64;              // in-row, replicated tail index
    float tmask = (lane < 8) ? 1.0f : 0.0f;  // tail contribution mask

    bool wx = (sx > ex), wy = (sy > ey);
    int off[8];
    float sgn[8];
    if (!wx && !wy) {
        prep_query(sx, sy, ex, ey, off, sgn);
        gather<4>(sat, off, sgn, lane, widx, tmask, acc_a, acc_b);
    } else if (wx && !wy) {
        prep_query(sx, sy, bru, ey, off, sgn);
        prep_query(tlu, sy, ex, ey, off + 4, sgn + 4);
        gather<8>(sat, off, sgn, lane, widx, tmask, acc_a, acc_b);
    } else if (!wx && wy) {
        prep_query(sx, sy, ex, brv, off, sgn);
        prep_query(sx, tlv, ex, ey, off + 4, sgn + 4);
        gather<8>(sat, off, sgn, lane, widx, tmask, acc_a, acc_b);
    } else {
        prep_query(tlu, tlv, ex, ey, off, sgn);
        prep_query(sx, sy, bru, brv, off + 4, sgn + 4);
        gather<8>(sat, off, sgn, lane, widx, tmask, acc_a, acc_b);
        prep_query(sx, tlv, bru, ey, off, sgn);
        prep_query(tlu, sy, ex, brv, off + 4, sgn + 4);
        gather<8>(sat, off, sgn, lane, widx, tmask, acc_a, acc_b);
    }

    // Streaming output: nontemporal so the 151 MB write stream doesn't evict
    // sat from Infinity Cache (sat is 302 MB vs 256 MB L3 -> retention matters).
    f32x4* __restrict__ orow = (f32x4*)(out + (size_t)wave * Cdim);
    __builtin_nontemporal_store(acc_a, orow + lane);
    if (lane < 8) __builtin_nontemporal_store(acc_b, orow + lane + 64);
}

extern "C" void kernel_launch(void* const* d_in, const int* in_sizes, int n_in,
                              void* d_out, int out_size, void* d_ws, size_t ws_size,
                              hipStream_t stream) {
    const float* sat = (const float*)d_in[0];
    const float* x   = (const float*)d_in[1];
    // d_in[2]=start_idx (-1), d_in[3]=len_idx: out_size == N*288 pins the
    // no-slice path, so they are ignored.
    float* out = (float*)d_out;
    int n = in_sizes[1] / 4;  // x is (N,4)

    int rows_per_block = 4;  // 256 threads = 4 waves
    int blocks = (n + rows_per_block - 1) / rows_per_block;
    sat_query_kernel<<<dim3(blocks), dim3(256), 0, stream>>>(sat, x, out, n);
}